// Round 9
// baseline (5012.701 us; speedup 1.0000x reference)
//
#include <hip/hip_runtime.h>
#include <stdint.h>

#define TSTEPS 512
#define BATCH  64
#define HDIM   512
#define GATE   2048
#define ACTMAT (BATCH * HDIM)   // 32768 activations per timestep matrix
#define SENT   0xFFFFFFFFu      // f16 NaN-pair sentinel; |h|<1 so never produced
#define NWORK  128              // 2 layers x 64 slices

typedef __attribute__((ext_vector_type(8))) _Float16 f16x8;
typedef __attribute__((ext_vector_type(4))) float f32x4;
typedef __attribute__((ext_vector_type(4))) uint32_t u32x4;

__device__ __forceinline__ unsigned short f2h(float f) {
  union { _Float16 h; unsigned short u; } v;
  v.h = (_Float16)f;                                 // RNE f32->f16
  return v.u;
}
__device__ __forceinline__ float fsigmoid(float x) {
  return 1.0f / (1.0f + __expf(-x));
}

// ---------------- pre-kernels ----------------

// Fill h histories with sentinel (t=0 slice = 0).
__global__ void init_h(unsigned short* h0, unsigned short* h1) {
  size_t u = (size_t)blockIdx.x * blockDim.x + threadIdx.x;   // 16B unit index
  u32x4 v;
  if (u < (ACTMAT * 2 / 16)) v = (u32x4){0u, 0u, 0u, 0u};
  else                       v = (u32x4){SENT, SENT, SENT, SENT};
  ((u32x4*)h0)[u] = v;
  ((u32x4*)h1)[u] = v;
}

__global__ void convert_x(const float* __restrict__ x, unsigned short* __restrict__ xh) {
  size_t i = (size_t)(blockIdx.x * blockDim.x + threadIdx.x) * 4;
  float4 v = *(const float4*)(x + i);
  ushort4 o = make_ushort4(f2h(v.x), f2h(v.y), f2h(v.z), f2h(v.w));
  *(ushort4*)(xh + i) = o;
}

// Fuse [Wi | Wh] into [GATE][1024], single f16 panel.
__global__ void split_w(const float* __restrict__ Wi, const float* __restrict__ Wh,
                        unsigned short* __restrict__ Wf) {
  int i = blockIdx.x * blockDim.x + threadIdx.x;     // over GATE*1024
  int G = i >> 10, k = i & 1023;
  float w = (k < 512) ? Wi[((size_t)G << 9) + k] : Wh[((size_t)G << 9) + (k - 512)];
  Wf[i] = f2h(w);
}

// ---------------- persistent recurrence kernel ----------------
// Round-6 structure (proven 4719us PASS) with ONE change: the h-store is coalesced.
// Threads deposit their packed (j,j+1) dwords into a 1KB LDS tile; after
// __syncthreads, wave 0's 64 lanes each emit ONE 16B global_store_dwordx4 sc0 sc1
// covering (b, j0..j0+7) -- 64 vector stores/WG/step instead of 256 scattered 4B
// system-scope stores. Theory: fine-grained remote-store settlement through the
// fabric is the invariant ~8us/step cost all three previous protocols measured.
// Race-safe: no consumer passes VALIDATE without this WG's own wave-0 stores
// being visible, so hx cannot be overwritten before wave 0 reads it.

__global__ __launch_bounds__(256, 1)
void sublstm_persistent(const unsigned short* __restrict__ xh,
                        unsigned short* h0, unsigned short* h1,
                        const unsigned short* __restrict__ Wf0,
                        const unsigned short* __restrict__ Wf1,
                        const float* __restrict__ bi0, const float* __restrict__ bi1,
                        float* __restrict__ out)
{
  __shared__ unsigned short wlds[32][1024];          // 64 KiB: [n][k] f16 bits
  __shared__ uint32_t hx[64][4];                     // 1 KiB h-store transpose tile

  const int wg    = blockIdx.x;
  const int tid   = threadIdx.x;
  const int layer = wg >> 6;
  const int slice = wg & 63;
  const int j0    = slice << 3;                      // first owned h-column
  const int lane  = tid & 63;
  const int wv    = tid >> 6;                        // wave 0..3 (b-tile)

  const unsigned short* Wf = layer ? Wf1 : Wf0;
  const float* bi = layer ? bi1 : bi0;

  // stage weight slice into LDS (16B units, unit index XOR-swizzled by n&15)
  for (int idx = tid; idx < 4096; idx += 256) {
    int n = (idx >> 7) & 31;                         // local gate row
    int u = idx & 127;                               // 16B unit within row
    int G = ((n & 3) << 9) + j0 + ((((n & 15) >> 2)) << 1) + (n >> 4);
    const unsigned short* s = Wf + ((size_t)G << 10) + ((size_t)u << 3);
    *(uint4*)&wlds[n][(u ^ (n & 15)) << 3] = *(const uint4*)s;
  }
  __syncthreads();

  const int c15 = lane & 15;
  const int g4  = lane >> 4;
  const int n0 = c15, n1 = 16 + c15;
  const int sw = c15;                                // XOR swizzle key
  const int b    = (wv << 4) + c15;                  // batch row this lane owns
  const int jcol0 = j0 + (g4 << 1);                  // even h-col; pair (jcol0, jcol0+1)
  const size_t arow = (size_t)b * HDIM;
  const size_t hoff0 = arow + jcol0;

  const float b00 = bi[jcol0],        b01 = bi[512 + jcol0];
  const float b02 = bi[1024 + jcol0], b03 = bi[1536 + jcol0];
  const float b10 = bi[jcol0 + 1],        b11 = bi[512 + jcol0 + 1];
  const float b12 = bi[1024 + jcol0 + 1], b13 = bi[1536 + jcol0 + 1];

  float c0 = 0.0f, c1 = 0.0f;                        // cell state, in regs all 512 steps

#define CONSUME(R, KK, UB) do {                                                        \
    f16x8 a = __builtin_bit_cast(f16x8, (R));                                          \
    int u_ = ((UB) + ((KK) << 2) + g4) ^ sw;                                           \
    f16x8 w0 = *(const f16x8*)&wlds[n0][u_ << 3];                                      \
    f16x8 w1 = *(const f16x8*)&wlds[n1][u_ << 3];                                      \
    acc0 = __builtin_amdgcn_mfma_f32_16x16x32_f16(w0, a, acc0, 0, 0, 0);               \
    acc1 = __builtin_amdgcn_mfma_f32_16x16x32_f16(w1, a, acc1, 0, 0, 0);               \
  } while (0)

#define CONSUME_ALL(P, UB)                                                             \
    CONSUME(P##0, 0, UB);  CONSUME(P##1, 1, UB);  CONSUME(P##2, 2, UB);                \
    CONSUME(P##3, 3, UB);  CONSUME(P##4, 4, UB);  CONSUME(P##5, 5, UB);                \
    CONSUME(P##6, 6, UB);  CONSUME(P##7, 7, UB);  CONSUME(P##8, 8, UB);                \
    CONSUME(P##9, 9, UB);  CONSUME(P##10, 10, UB); CONSUME(P##11, 11, UB);             \
    CONSUME(P##12, 12, UB); CONSUME(P##13, 13, UB); CONSUME(P##14, 14, UB);            \
    CONSUME(P##15, 15, UB)

#define LD1(R, OFFTOK, HP)                                                             \
    asm volatile("global_load_dwordx4 %0, %1, off " OFFTOK " sc0 sc1"                  \
                 : "=v"(R) : "v"(HP) : "memory")

#define ISSUE16(HP, P) do {                                                            \
    LD1(P##0, "", HP);            LD1(P##1, "offset:64", HP);                          \
    LD1(P##2, "offset:128", HP);  LD1(P##3, "offset:192", HP);                         \
    LD1(P##4, "offset:256", HP);  LD1(P##5, "offset:320", HP);                         \
    LD1(P##6, "offset:384", HP);  LD1(P##7, "offset:448", HP);                         \
    LD1(P##8, "offset:512", HP);  LD1(P##9, "offset:576", HP);                         \
    LD1(P##10, "offset:640", HP); LD1(P##11, "offset:704", HP);                        \
    LD1(P##12, "offset:768", HP); LD1(P##13, "offset:832", HP);                        \
    LD1(P##14, "offset:896", HP); LD1(P##15, "offset:960", HP);                        \
  } while (0)

#define BAD1(R) ((R[0] == SENT) | (R[1] == SENT) | (R[2] == SENT) | (R[3] == SENT))

#define VALIDATE(HP, P) do {                                                           \
    for (;;) {                                                                         \
      asm volatile("s_waitcnt vmcnt(0)" ::: "memory");                                 \
      __builtin_amdgcn_sched_barrier(0);                                               \
      int bad_ = BAD1(P##0) | BAD1(P##1) | BAD1(P##2) | BAD1(P##3) |                   \
                 BAD1(P##4) | BAD1(P##5) | BAD1(P##6) | BAD1(P##7) |                   \
                 BAD1(P##8) | BAD1(P##9) | BAD1(P##10) | BAD1(P##11) |                 \
                 BAD1(P##12) | BAD1(P##13) | BAD1(P##14) | BAD1(P##15);                \
      if (!__any(bad_)) break;                                                         \
      ISSUE16(HP, P);                                                                  \
    }                                                                                  \
    __builtin_amdgcn_sched_barrier(0);                                                 \
  } while (0)

// x half: plain cached loads (xh is read-only input, L2-resident per XCD)
#define KHALF_X(AP) do {                                                               \
    const unsigned short* ap_ = (AP) + arow + (g4 << 3);                               \
    _Pragma("unroll")                                                                  \
    for (int kk = 0; kk < 16; ++kk) {                                                  \
      u32x4 rr = *(const u32x4*)(ap_ + (kk << 5));                                     \
      CONSUME(rr, kk, 0);                                                              \
    }                                                                                  \
  } while (0)

#define EPILOGUE(T) do {                                                               \
    unsigned short* hn = (layer ? h1 : h0) + (size_t)((T) + 1) * ACTMAT;               \
    float gi0 = fsigmoid(acc0[0] + b00), go0 = fsigmoid(acc0[1] + b01);                \
    float gz0 = fsigmoid(acc0[2] + b02), gf0 = fsigmoid(acc0[3] + b03);                \
    c0 = c0 * gf0 + gz0 - gi0;                                                         \
    float hv0 = fsigmoid(c0) - go0;                                                    \
    float gi1 = fsigmoid(acc1[0] + b10), go1 = fsigmoid(acc1[1] + b11);                \
    float gz1 = fsigmoid(acc1[2] + b12), gf1 = fsigmoid(acc1[3] + b13);                \
    c1 = c1 * gf1 + gz1 - gi1;                                                         \
    float hv1 = fsigmoid(c1) - go1;                                                    \
    uint32_t hw = (uint32_t)f2h(hv0) | ((uint32_t)f2h(hv1) << 16);                     \
    hx[b][g4] = hw;                                                                    \
    __syncthreads();                                                                   \
    if (tid < 64) {                                                                    \
      u32x4 hv = *(const u32x4*)&hx[tid][0];                                           \
      asm volatile("global_store_dwordx4 %0, %1, off sc0 sc1"                          \
                   :: "v"(hn + (size_t)tid * HDIM + j0), "v"(hv) : "memory");          \
    }                                                                                  \
    if (layer) {                                                                       \
      float* outp = out + (size_t)(T) * ACTMAT;                                        \
      *(float2*)(outp + hoff0) = make_float2(hv0, hv1);                                \
    }                                                                                  \
  } while (0)

  if (layer == 0) {
    for (int t = 0; t < TSTEPS; ++t) {
      f32x4 acc0 = {}, acc1 = {};
      u32x4 ra0, ra1, ra2, ra3, ra4, ra5, ra6, ra7,
            ra8, ra9, ra10, ra11, ra12, ra13, ra14, ra15;
      const unsigned short* hp = h0 + (size_t)t * ACTMAT + arow + (g4 << 3);
      ISSUE16(hp, ra);                               // speculative: hide RT under x-half
      KHALF_X(xh + (size_t)t * ACTMAT);              // independent work (32 MFMAs)
      VALIDATE(hp, ra);                              // sentinel check, re-issue if stale
      CONSUME_ALL(ra, 64);
      EPILOGUE(t);
    }
  } else {
    for (int t = 0; t < TSTEPS; ++t) {
      f32x4 acc0 = {}, acc1 = {};
      u32x4 ra0, ra1, ra2, ra3, ra4, ra5, ra6, ra7,
            ra8, ra9, ra10, ra11, ra12, ra13, ra14, ra15;
      u32x4 rb0, rb1, rb2, rb3, rb4, rb5, rb6, rb7,
            rb8, rb9, rb10, rb11, rb12, rb13, rb14, rb15;
      const unsigned short* hpA = h1 + (size_t)t * ACTMAT + arow + (g4 << 3);
      const unsigned short* hpB = h0 + (size_t)(t + 1) * ACTMAT + arow + (g4 << 3);
      ISSUE16(hpA, ra);                              // own h1[t]: almost always landed
      ISSUE16(hpB, rb);                              // layer0's h0[t+1]: the late one
      VALIDATE(hpA, ra);
      CONSUME_ALL(ra, 64);                           // 32 MFMAs hide hpB's round trip
      VALIDATE(hpB, rb);
      CONSUME_ALL(rb, 0);
      EPILOGUE(t);
    }
  }
#undef CONSUME
#undef CONSUME_ALL
#undef LD1
#undef ISSUE16
#undef BAD1
#undef VALIDATE
#undef KHALF_X
#undef EPILOGUE
}

// ---------------- launch ----------------

extern "C" void kernel_launch(void* const* d_in, const int* in_sizes, int n_in,
                              void* d_out, int out_size, void* d_ws, size_t ws_size,
                              hipStream_t stream) {
  (void)in_sizes; (void)n_in; (void)out_size; (void)ws_size;
  const float* x   = (const float*)d_in[0];
  const float* Wi0 = (const float*)d_in[1];
  const float* bi0 = (const float*)d_in[2];
  const float* Wh0 = (const float*)d_in[3];
  const float* Wi1 = (const float*)d_in[4];
  const float* bi1 = (const float*)d_in[5];
  const float* Wh1 = (const float*)d_in[6];
  float* out = (float*)d_out;

  char* ws = (char*)d_ws;
  size_t off = 0;
  auto take = [&](size_t bytes) -> void* {
    void* p = ws + off;
    off += (bytes + 255) & ~(size_t)255;
    return p;
  };
  unsigned short* xh  = (unsigned short*)take((size_t)TSTEPS * ACTMAT * 2);        // 33.5 MB
  unsigned short* h0  = (unsigned short*)take((size_t)(TSTEPS + 1) * ACTMAT * 2);  // 33.6 MB
  unsigned short* h1  = (unsigned short*)take((size_t)(TSTEPS + 1) * ACTMAT * 2);  // 33.6 MB
  unsigned short* Wf0 = (unsigned short*)take((size_t)GATE * 1024 * 2);            // 4 MB
  unsigned short* Wf1 = (unsigned short*)take((size_t)GATE * 1024 * 2);            // 4 MB

  // (TSTEPS+1)*ACTMAT ushorts = 33,619,968 B per buffer -> 2,101,248 16B units
  init_h<<<dim3(8208), dim3(256), 0, stream>>>(h0, h1);
  convert_x<<<dim3(16384), dim3(256), 0, stream>>>(x, xh);
  split_w<<<dim3(8192), dim3(256), 0, stream>>>(Wi0, Wh0, Wf0);
  split_w<<<dim3(8192), dim3(256), 0, stream>>>(Wi1, Wh1, Wf1);
  sublstm_persistent<<<dim3(NWORK), dim3(256), 0, stream>>>(
      xh, h0, h1, Wf0, Wf1, bi0, bi1, out);
}

// Round 10
// 4902.482 us; speedup vs baseline: 1.0225x; 1.0225x over previous
//
#include <hip/hip_runtime.h>
#include <stdint.h>

#define TSTEPS 512
#define BATCH  64
#define HDIM   512
#define GATE   2048
#define ACTMAT (BATCH * HDIM)   // 32768 activations per timestep matrix
#define SENT   0xFFFFFFFFu      // f16 NaN-pair sentinel; |h|<1 so never produced
#define NWORK  128              // 2 layers x 64 slices

typedef __attribute__((ext_vector_type(8))) _Float16 f16x8;
typedef __attribute__((ext_vector_type(4))) float f32x4;
typedef __attribute__((ext_vector_type(4))) uint32_t u32x4;

__device__ __forceinline__ unsigned short f2h(float f) {
  union { _Float16 h; unsigned short u; } v;
  v.h = (_Float16)f;                                 // RNE f32->f16
  return v.u;
}
__device__ __forceinline__ float fsigmoid(float x) {
  return 1.0f / (1.0f + __expf(-x));
}

// ---------------- pre-kernels ----------------

// Fill h histories with sentinel (t=0 slice = 0).
__global__ void init_h(unsigned short* h0, unsigned short* h1) {
  size_t u = (size_t)blockIdx.x * blockDim.x + threadIdx.x;   // 16B unit index
  u32x4 v;
  if (u < (ACTMAT * 2 / 16)) v = (u32x4){0u, 0u, 0u, 0u};
  else                       v = (u32x4){SENT, SENT, SENT, SENT};
  ((u32x4*)h0)[u] = v;
  ((u32x4*)h1)[u] = v;
}

__global__ void convert_x(const float* __restrict__ x, unsigned short* __restrict__ xh) {
  size_t i = (size_t)(blockIdx.x * blockDim.x + threadIdx.x) * 4;
  float4 v = *(const float4*)(x + i);
  ushort4 o = make_ushort4(f2h(v.x), f2h(v.y), f2h(v.z), f2h(v.w));
  *(ushort4*)(xh + i) = o;
}

// Fuse [Wi | Wh] into [GATE][1024], single f16 panel.
__global__ void split_w(const float* __restrict__ Wi, const float* __restrict__ Wh,
                        unsigned short* __restrict__ Wf) {
  int i = blockIdx.x * blockDim.x + threadIdx.x;     // over GATE*1024
  int G = i >> 10, k = i & 1023;
  float w = (k < 512) ? Wi[((size_t)G << 9) + k] : Wh[((size_t)G << 9) + (k - 512)];
  Wf[i] = f2h(w);
}

// ---------------- persistent recurrence kernel ----------------
// Round-6 structure (proven 4719us PASS) with ONE change: SELECTIVE RE-ISSUE in the
// sentinel spin. Previous VALIDATE re-issued all 16 dwordx4 loads per retry (64KB/WG)
// -> 128 spinning WGs generate ~10TB/s of system-scope bypass traffic, congesting the
// fabric/MALL and inflating the very round-trip the spin waits on. Now each retry
// re-issues ONLY registers whose quad still holds a sentinel (__any-uniform branch):
// steady-state spin bandwidth drops ~16x. Race-free: each h dword is written exactly
// once per step, so valid data never regresses to sentinel.

__global__ __launch_bounds__(256, 1)
void sublstm_persistent(const unsigned short* __restrict__ xh,
                        unsigned short* h0, unsigned short* h1,
                        const unsigned short* __restrict__ Wf0,
                        const unsigned short* __restrict__ Wf1,
                        const float* __restrict__ bi0, const float* __restrict__ bi1,
                        float* __restrict__ out)
{
  __shared__ unsigned short wlds[32][1024];          // 64 KiB: [n][k] f16 bits

  const int wg    = blockIdx.x;
  const int tid   = threadIdx.x;
  const int layer = wg >> 6;
  const int slice = wg & 63;
  const int j0    = slice << 3;                      // first owned h-column
  const int lane  = tid & 63;
  const int wv    = tid >> 6;                        // wave 0..3 (b-tile)

  const unsigned short* Wf = layer ? Wf1 : Wf0;
  const float* bi = layer ? bi1 : bi0;

  // stage weight slice into LDS (16B units, unit index XOR-swizzled by n&15)
  for (int idx = tid; idx < 4096; idx += 256) {
    int n = (idx >> 7) & 31;                         // local gate row
    int u = idx & 127;                               // 16B unit within row
    int G = ((n & 3) << 9) + j0 + ((((n & 15) >> 2)) << 1) + (n >> 4);
    const unsigned short* s = Wf + ((size_t)G << 10) + ((size_t)u << 3);
    *(uint4*)&wlds[n][(u ^ (n & 15)) << 3] = *(const uint4*)s;
  }
  __syncthreads();

  const int c15 = lane & 15;
  const int g4  = lane >> 4;
  const int n0 = c15, n1 = 16 + c15;
  const int sw = c15;                                // XOR swizzle key
  const int b    = (wv << 4) + c15;                  // batch row this lane owns
  const int jcol0 = j0 + (g4 << 1);                  // even h-col; pair (jcol0, jcol0+1)
  const size_t arow = (size_t)b * HDIM;
  const size_t hoff0 = arow + jcol0;

  const float b00 = bi[jcol0],        b01 = bi[512 + jcol0];
  const float b02 = bi[1024 + jcol0], b03 = bi[1536 + jcol0];
  const float b10 = bi[jcol0 + 1],        b11 = bi[512 + jcol0 + 1];
  const float b12 = bi[1024 + jcol0 + 1], b13 = bi[1536 + jcol0 + 1];

  float c0 = 0.0f, c1 = 0.0f;                        // cell state, in regs all 512 steps

#define CONSUME(R, KK, UB) do {                                                        \
    f16x8 a = __builtin_bit_cast(f16x8, (R));                                          \
    int u_ = ((UB) + ((KK) << 2) + g4) ^ sw;                                           \
    f16x8 w0 = *(const f16x8*)&wlds[n0][u_ << 3];                                      \
    f16x8 w1 = *(const f16x8*)&wlds[n1][u_ << 3];                                      \
    acc0 = __builtin_amdgcn_mfma_f32_16x16x32_f16(w0, a, acc0, 0, 0, 0);               \
    acc1 = __builtin_amdgcn_mfma_f32_16x16x32_f16(w1, a, acc1, 0, 0, 0);               \
  } while (0)

#define CONSUME_ALL(P, UB)                                                             \
    CONSUME(P##0, 0, UB);  CONSUME(P##1, 1, UB);  CONSUME(P##2, 2, UB);                \
    CONSUME(P##3, 3, UB);  CONSUME(P##4, 4, UB);  CONSUME(P##5, 5, UB);                \
    CONSUME(P##6, 6, UB);  CONSUME(P##7, 7, UB);  CONSUME(P##8, 8, UB);                \
    CONSUME(P##9, 9, UB);  CONSUME(P##10, 10, UB); CONSUME(P##11, 11, UB);             \
    CONSUME(P##12, 12, UB); CONSUME(P##13, 13, UB); CONSUME(P##14, 14, UB);            \
    CONSUME(P##15, 15, UB)

#define LD1(R, OFFTOK, HP)                                                             \
    asm volatile("global_load_dwordx4 %0, %1, off " OFFTOK " sc0 sc1"                  \
                 : "=v"(R) : "v"(HP) : "memory")

#define ISSUE16(HP, P) do {                                                            \
    LD1(P##0, "", HP);            LD1(P##1, "offset:64", HP);                          \
    LD1(P##2, "offset:128", HP);  LD1(P##3, "offset:192", HP);                         \
    LD1(P##4, "offset:256", HP);  LD1(P##5, "offset:320", HP);                         \
    LD1(P##6, "offset:384", HP);  LD1(P##7, "offset:448", HP);                         \
    LD1(P##8, "offset:512", HP);  LD1(P##9, "offset:576", HP);                         \
    LD1(P##10, "offset:640", HP); LD1(P##11, "offset:704", HP);                        \
    LD1(P##12, "offset:768", HP); LD1(P##13, "offset:832", HP);                        \
    LD1(P##14, "offset:896", HP); LD1(P##15, "offset:960", HP);                        \
  } while (0)

#define BAD1(R) ((R[0] == SENT) | (R[1] == SENT) | (R[2] == SENT) | (R[3] == SENT))

// Selective re-issue: per retry, only registers whose quad still holds a sentinel
// are re-loaded (wave-uniform __any branch). Cuts steady spin traffic ~16x.
#define RETRY1(P, OFFTOK, HP) \
    if (__any(BAD1(P))) { LD1(P, OFFTOK, HP); ++nbad_; }

#define VALIDATE(HP, P) do {                                                           \
    for (;;) {                                                                         \
      asm volatile("s_waitcnt vmcnt(0)" ::: "memory");                                 \
      __builtin_amdgcn_sched_barrier(0);                                               \
      int nbad_ = 0;                                                                   \
      RETRY1(P##0, "", HP);            RETRY1(P##1, "offset:64", HP);                  \
      RETRY1(P##2, "offset:128", HP);  RETRY1(P##3, "offset:192", HP);                 \
      RETRY1(P##4, "offset:256", HP);  RETRY1(P##5, "offset:320", HP);                 \
      RETRY1(P##6, "offset:384", HP);  RETRY1(P##7, "offset:448", HP);                 \
      RETRY1(P##8, "offset:512", HP);  RETRY1(P##9, "offset:576", HP);                 \
      RETRY1(P##10, "offset:640", HP); RETRY1(P##11, "offset:704", HP);                \
      RETRY1(P##12, "offset:768", HP); RETRY1(P##13, "offset:832", HP);                \
      RETRY1(P##14, "offset:896", HP); RETRY1(P##15, "offset:960", HP);                \
      if (!nbad_) break;                                                               \
    }                                                                                  \
    __builtin_amdgcn_sched_barrier(0);                                                 \
  } while (0)

// x half: plain cached loads (xh is read-only input, L2-resident per XCD)
#define KHALF_X(AP) do {                                                               \
    const unsigned short* ap_ = (AP) + arow + (g4 << 3);                               \
    _Pragma("unroll")                                                                  \
    for (int kk = 0; kk < 16; ++kk) {                                                  \
      u32x4 rr = *(const u32x4*)(ap_ + (kk << 5));                                     \
      CONSUME(rr, kk, 0);                                                              \
    }                                                                                  \
  } while (0)

#define EPILOGUE(T) do {                                                               \
    unsigned short* hn = (layer ? h1 : h0) + (size_t)((T) + 1) * ACTMAT;               \
    float gi0 = fsigmoid(acc0[0] + b00), go0 = fsigmoid(acc0[1] + b01);                \
    float gz0 = fsigmoid(acc0[2] + b02), gf0 = fsigmoid(acc0[3] + b03);                \
    c0 = c0 * gf0 + gz0 - gi0;                                                         \
    float hv0 = fsigmoid(c0) - go0;                                                    \
    float gi1 = fsigmoid(acc1[0] + b10), go1 = fsigmoid(acc1[1] + b11);                \
    float gz1 = fsigmoid(acc1[2] + b12), gf1 = fsigmoid(acc1[3] + b13);                \
    c1 = c1 * gf1 + gz1 - gi1;                                                         \
    float hv1 = fsigmoid(c1) - go1;                                                    \
    uint32_t hw = (uint32_t)f2h(hv0) | ((uint32_t)f2h(hv1) << 16);                     \
    __hip_atomic_store((uint32_t*)(hn + hoff0), hw, __ATOMIC_RELAXED,                  \
                       __HIP_MEMORY_SCOPE_AGENT);                                      \
    if (layer) {                                                                       \
      float* outp = out + (size_t)(T) * ACTMAT;                                        \
      *(float2*)(outp + hoff0) = make_float2(hv0, hv1);                                \
    }                                                                                  \
  } while (0)

  if (layer == 0) {
    for (int t = 0; t < TSTEPS; ++t) {
      f32x4 acc0 = {}, acc1 = {};
      u32x4 ra0, ra1, ra2, ra3, ra4, ra5, ra6, ra7,
            ra8, ra9, ra10, ra11, ra12, ra13, ra14, ra15;
      const unsigned short* hp = h0 + (size_t)t * ACTMAT + arow + (g4 << 3);
      ISSUE16(hp, ra);                               // speculative: hide RT under x-half
      KHALF_X(xh + (size_t)t * ACTMAT);              // independent work (32 MFMAs)
      VALIDATE(hp, ra);                              // selective sentinel spin
      CONSUME_ALL(ra, 64);
      EPILOGUE(t);
    }
  } else {
    for (int t = 0; t < TSTEPS; ++t) {
      f32x4 acc0 = {}, acc1 = {};
      u32x4 ra0, ra1, ra2, ra3, ra4, ra5, ra6, ra7,
            ra8, ra9, ra10, ra11, ra12, ra13, ra14, ra15;
      u32x4 rb0, rb1, rb2, rb3, rb4, rb5, rb6, rb7,
            rb8, rb9, rb10, rb11, rb12, rb13, rb14, rb15;
      const unsigned short* hpA = h1 + (size_t)t * ACTMAT + arow + (g4 << 3);
      const unsigned short* hpB = h0 + (size_t)(t + 1) * ACTMAT + arow + (g4 << 3);
      ISSUE16(hpA, ra);                              // own h1[t]: almost always landed
      ISSUE16(hpB, rb);                              // layer0's h0[t+1]: the late one
      VALIDATE(hpA, ra);
      CONSUME_ALL(ra, 64);                           // 32 MFMAs hide hpB's round trip
      VALIDATE(hpB, rb);
      CONSUME_ALL(rb, 0);
      EPILOGUE(t);
    }
  }
#undef CONSUME
#undef CONSUME_ALL
#undef LD1
#undef ISSUE16
#undef BAD1
#undef RETRY1
#undef VALIDATE
#undef KHALF_X
#undef EPILOGUE
}

// ---------------- launch ----------------

extern "C" void kernel_launch(void* const* d_in, const int* in_sizes, int n_in,
                              void* d_out, int out_size, void* d_ws, size_t ws_size,
                              hipStream_t stream) {
  (void)in_sizes; (void)n_in; (void)out_size; (void)ws_size;
  const float* x   = (const float*)d_in[0];
  const float* Wi0 = (const float*)d_in[1];
  const float* bi0 = (const float*)d_in[2];
  const float* Wh0 = (const float*)d_in[3];
  const float* Wi1 = (const float*)d_in[4];
  const float* bi1 = (const float*)d_in[5];
  const float* Wh1 = (const float*)d_in[6];
  float* out = (float*)d_out;

  char* ws = (char*)d_ws;
  size_t off = 0;
  auto take = [&](size_t bytes) -> void* {
    void* p = ws + off;
    off += (bytes + 255) & ~(size_t)255;
    return p;
  };
  unsigned short* xh  = (unsigned short*)take((size_t)TSTEPS * ACTMAT * 2);        // 33.5 MB
  unsigned short* h0  = (unsigned short*)take((size_t)(TSTEPS + 1) * ACTMAT * 2);  // 33.6 MB
  unsigned short* h1  = (unsigned short*)take((size_t)(TSTEPS + 1) * ACTMAT * 2);  // 33.6 MB
  unsigned short* Wf0 = (unsigned short*)take((size_t)GATE * 1024 * 2);            // 4 MB
  unsigned short* Wf1 = (unsigned short*)take((size_t)GATE * 1024 * 2);            // 4 MB

  // (TSTEPS+1)*ACTMAT ushorts = 33,619,968 B per buffer -> 2,101,248 16B units
  init_h<<<dim3(8208), dim3(256), 0, stream>>>(h0, h1);
  convert_x<<<dim3(16384), dim3(256), 0, stream>>>(x, xh);
  split_w<<<dim3(8192), dim3(256), 0, stream>>>(Wi0, Wh0, Wf0);
  split_w<<<dim3(8192), dim3(256), 0, stream>>>(Wi1, Wh1, Wf1);
  sublstm_persistent<<<dim3(NWORK), dim3(256), 0, stream>>>(
      xh, h0, h1, Wf0, Wf1, bi0, bi1, out);
}

// Round 11
// 3868.605 us; speedup vs baseline: 1.2957x; 1.2672x over previous
//
#include <hip/hip_runtime.h>
#include <stdint.h>

#define TSTEPS 512
#define BATCH  64
#define HDIM   512
#define GATE   2048
#define ACTMAT (BATCH * HDIM)   // 32768 activations per timestep matrix
#define SENT   0xFFFFFFFFu      // f16 NaN-pair sentinel; |h|<1 so never produced
#define NWORK  128              // 2 layers x (32 col-slices x 2 batch-halves)

typedef __attribute__((ext_vector_type(8))) _Float16 f16x8;
typedef __attribute__((ext_vector_type(4))) float f32x4;
typedef __attribute__((ext_vector_type(4))) uint32_t u32x4;
typedef __attribute__((ext_vector_type(2))) uint32_t u32x2;

__device__ __forceinline__ unsigned short f2h(float f) {
  union { _Float16 h; unsigned short u; } v;
  v.h = (_Float16)f;                                 // RNE f32->f16
  return v.u;
}
__device__ __forceinline__ float fsigmoid(float x) {
  return 1.0f / (1.0f + __expf(-x));
}

// ---------------- pre-kernels ----------------

// Fill h histories with sentinel (t=0 slice = 0).
__global__ void init_h(unsigned short* h0, unsigned short* h1) {
  size_t u = (size_t)blockIdx.x * blockDim.x + threadIdx.x;   // 16B unit index
  u32x4 v;
  if (u < (ACTMAT * 2 / 16)) v = (u32x4){0u, 0u, 0u, 0u};
  else                       v = (u32x4){SENT, SENT, SENT, SENT};
  ((u32x4*)h0)[u] = v;
  ((u32x4*)h1)[u] = v;
}

__global__ void convert_x(const float* __restrict__ x, unsigned short* __restrict__ xh) {
  size_t i = (size_t)(blockIdx.x * blockDim.x + threadIdx.x) * 4;
  float4 v = *(const float4*)(x + i);
  ushort4 o = make_ushort4(f2h(v.x), f2h(v.y), f2h(v.z), f2h(v.w));
  *(ushort4*)(xh + i) = o;
}

// Fuse [Wi | Wh] into [GATE][1024], single f16 panel.
__global__ void split_w(const float* __restrict__ Wi, const float* __restrict__ Wh,
                        unsigned short* __restrict__ Wf) {
  int i = blockIdx.x * blockDim.x + threadIdx.x;     // over GATE*1024
  int G = i >> 10, k = i & 1023;
  float w = (k < 512) ? Wi[((size_t)G << 9) + k] : Wh[((size_t)G << 9) + (k - 512)];
  Wf[i] = f2h(w);
}

// ---------------- persistent recurrence kernel ----------------
// GEOMETRY CHANGE vs round 6 (protocol identical): fatter WGs cut the all-to-all
// exchange volume 2x. 128 WGs x 128 threads (2 waves). WG = (32 batch rows x 16
// h-cols): layer = wg>>6; s = wg&31 -> j0 = s*16; p = (wg>>5)&1 -> rows p*32..+32.
// Wave wr covers 16 rows; each wave computes 4 MFMA n-tiles (64 gates), gate map
// G(n) = (n>>4)*512 + j0 + (n&15): lane (c15,g4) ends with 16 accs = 4 quadrants
// x 4 adjacent j (j0+4*g4..+3) for batch row (p*32+wr*16+c15) -> zero-shuffle
// epilogue, ONE 8B dwordx2 h-store per lane. Weights: full 16-col slice f16 in
// 128KB LDS (1 WG/CU). Per-WG bypass reads: 32KB (was 64KB); aggregate exchange
// 6MB/step (was 12MB). Sentinel data-as-flag protocol unchanged from round 6.

__global__ __launch_bounds__(128, 1)
void sublstm_persistent(const unsigned short* __restrict__ xh,
                        unsigned short* h0, unsigned short* h1,
                        const unsigned short* __restrict__ Wf0,
                        const unsigned short* __restrict__ Wf1,
                        const float* __restrict__ bi0, const float* __restrict__ bi1,
                        float* __restrict__ out)
{
  __shared__ unsigned short wlds[64][1024];          // 128 KiB: [n][k] f16 bits

  const int wg    = blockIdx.x;
  const int tid   = threadIdx.x;
  const int layer = wg >> 6;
  const int wgl   = wg & 63;
  const int s     = wgl & 31;
  const int p     = wgl >> 5;
  const int j0    = s << 4;                          // first owned h-column (16 cols)
  const int b0    = p << 5;                          // first owned batch row (32 rows)
  const int lane  = tid & 63;
  const int wr    = tid >> 6;                        // wave 0/1 = row-half

  const unsigned short* Wf = layer ? Wf1 : Wf0;
  const float* bi = layer ? bi1 : bi0;

  // stage weight slice into LDS (16B units, unit index XOR-swizzled by n&15)
  for (int idx = tid; idx < 8192; idx += 128) {
    int n = idx >> 7;                                // local gate row 0..63
    int u = idx & 127;                               // 16B unit within row
    int G = ((n >> 4) << 9) + j0 + (n & 15);         // gate = q*512 + j0 + jl
    const unsigned short* sp = Wf + ((size_t)G << 10) + ((size_t)u << 3);
    *(uint4*)&wlds[n][(u ^ (n & 15)) << 3] = *(const uint4*)sp;
  }
  __syncthreads();

  const int c15 = lane & 15;
  const int g4  = lane >> 4;
  const int sw  = c15;                               // XOR swizzle key
  const int brow = b0 + (wr << 4) + c15;             // batch row this lane owns
  const int jb   = j0 + (g4 << 2);                   // first of lane's 4 j-cols
  const size_t arow = (size_t)brow * HDIM;
  const size_t hoff = arow + jb;

  const float4 bq0 = *(const float4*)&bi[jb];        // i-gate bias, j jb..jb+3
  const float4 bq1 = *(const float4*)&bi[512 + jb];  // o
  const float4 bq2 = *(const float4*)&bi[1024 + jb]; // z
  const float4 bq3 = *(const float4*)&bi[1536 + jb]; // f

  float cs0 = 0.0f, cs1 = 0.0f, cs2 = 0.0f, cs3 = 0.0f;  // cell state, 4 j's

#define CONSUME(R, KK, UB) do {                                                        \
    f16x8 a = __builtin_bit_cast(f16x8, (R));                                          \
    int u_ = ((UB) + ((KK) << 2) + g4) ^ sw;                                           \
    f16x8 w0 = *(const f16x8*)&wlds[c15][u_ << 3];                                     \
    f16x8 w1 = *(const f16x8*)&wlds[16 + c15][u_ << 3];                                \
    f16x8 w2 = *(const f16x8*)&wlds[32 + c15][u_ << 3];                                \
    f16x8 w3 = *(const f16x8*)&wlds[48 + c15][u_ << 3];                                \
    acc0 = __builtin_amdgcn_mfma_f32_16x16x32_f16(w0, a, acc0, 0, 0, 0);               \
    acc1 = __builtin_amdgcn_mfma_f32_16x16x32_f16(w1, a, acc1, 0, 0, 0);               \
    acc2 = __builtin_amdgcn_mfma_f32_16x16x32_f16(w2, a, acc2, 0, 0, 0);               \
    acc3 = __builtin_amdgcn_mfma_f32_16x16x32_f16(w3, a, acc3, 0, 0, 0);               \
  } while (0)

#define CONSUME_ALL(P, UB)                                                             \
    CONSUME(P##0, 0, UB);  CONSUME(P##1, 1, UB);  CONSUME(P##2, 2, UB);                \
    CONSUME(P##3, 3, UB);  CONSUME(P##4, 4, UB);  CONSUME(P##5, 5, UB);                \
    CONSUME(P##6, 6, UB);  CONSUME(P##7, 7, UB);  CONSUME(P##8, 8, UB);                \
    CONSUME(P##9, 9, UB);  CONSUME(P##10, 10, UB); CONSUME(P##11, 11, UB);             \
    CONSUME(P##12, 12, UB); CONSUME(P##13, 13, UB); CONSUME(P##14, 14, UB);            \
    CONSUME(P##15, 15, UB)

#define LD1(R, OFFTOK, HP)                                                             \
    asm volatile("global_load_dwordx4 %0, %1, off " OFFTOK " sc0 sc1"                  \
                 : "=v"(R) : "v"(HP) : "memory")

#define ISSUE16(HP, P) do {                                                            \
    LD1(P##0, "", HP);            LD1(P##1, "offset:64", HP);                          \
    LD1(P##2, "offset:128", HP);  LD1(P##3, "offset:192", HP);                         \
    LD1(P##4, "offset:256", HP);  LD1(P##5, "offset:320", HP);                         \
    LD1(P##6, "offset:384", HP);  LD1(P##7, "offset:448", HP);                         \
    LD1(P##8, "offset:512", HP);  LD1(P##9, "offset:576", HP);                         \
    LD1(P##10, "offset:640", HP); LD1(P##11, "offset:704", HP);                        \
    LD1(P##12, "offset:768", HP); LD1(P##13, "offset:832", HP);                        \
    LD1(P##14, "offset:896", HP); LD1(P##15, "offset:960", HP);                        \
  } while (0)

#define BAD1(R) ((R[0] == SENT) | (R[1] == SENT) | (R[2] == SENT) | (R[3] == SENT))

#define VALIDATE(HP, P) do {                                                           \
    for (;;) {                                                                         \
      asm volatile("s_waitcnt vmcnt(0)" ::: "memory");                                 \
      __builtin_amdgcn_sched_barrier(0);                                               \
      int bad_ = BAD1(P##0) | BAD1(P##1) | BAD1(P##2) | BAD1(P##3) |                   \
                 BAD1(P##4) | BAD1(P##5) | BAD1(P##6) | BAD1(P##7) |                   \
                 BAD1(P##8) | BAD1(P##9) | BAD1(P##10) | BAD1(P##11) |                 \
                 BAD1(P##12) | BAD1(P##13) | BAD1(P##14) | BAD1(P##15);                \
      if (!__any(bad_)) break;                                                         \
      ISSUE16(HP, P);                                                                  \
    }                                                                                  \
    __builtin_amdgcn_sched_barrier(0);                                                 \
  } while (0)

// x half: plain cached loads (xh is read-only input, L2-resident per XCD)
#define KHALF_X(AP) do {                                                               \
    const unsigned short* ap_ = (AP) + arow + (g4 << 3);                               \
    _Pragma("unroll")                                                                  \
    for (int kk = 0; kk < 16; ++kk) {                                                  \
      u32x4 rr = *(const u32x4*)(ap_ + (kk << 5));                                     \
      CONSUME(rr, kk, 0);                                                              \
    }                                                                                  \
  } while (0)

#define EPILOGUE(T) do {                                                               \
    unsigned short* hn = (layer ? h1 : h0) + (size_t)((T) + 1) * ACTMAT;               \
    float gi_, go_, gz_, gf_, h0v, h1v, h2v, h3v;                                      \
    gi_ = fsigmoid(acc0[0] + bq0.x); go_ = fsigmoid(acc1[0] + bq1.x);                  \
    gz_ = fsigmoid(acc2[0] + bq2.x); gf_ = fsigmoid(acc3[0] + bq3.x);                  \
    cs0 = cs0 * gf_ + gz_ - gi_;  h0v = fsigmoid(cs0) - go_;                           \
    gi_ = fsigmoid(acc0[1] + bq0.y); go_ = fsigmoid(acc1[1] + bq1.y);                  \
    gz_ = fsigmoid(acc2[1] + bq2.y); gf_ = fsigmoid(acc3[1] + bq3.y);                  \
    cs1 = cs1 * gf_ + gz_ - gi_;  h1v = fsigmoid(cs1) - go_;                           \
    gi_ = fsigmoid(acc0[2] + bq0.z); go_ = fsigmoid(acc1[2] + bq1.z);                  \
    gz_ = fsigmoid(acc2[2] + bq2.z); gf_ = fsigmoid(acc3[2] + bq3.z);                  \
    cs2 = cs2 * gf_ + gz_ - gi_;  h2v = fsigmoid(cs2) - go_;                           \
    gi_ = fsigmoid(acc0[3] + bq0.w); go_ = fsigmoid(acc1[3] + bq1.w);                  \
    gz_ = fsigmoid(acc2[3] + bq2.w); gf_ = fsigmoid(acc3[3] + bq3.w);                  \
    cs3 = cs3 * gf_ + gz_ - gi_;  h3v = fsigmoid(cs3) - go_;                           \
    u32x2 dv;                                                                          \
    dv[0] = (uint32_t)f2h(h0v) | ((uint32_t)f2h(h1v) << 16);                           \
    dv[1] = (uint32_t)f2h(h2v) | ((uint32_t)f2h(h3v) << 16);                           \
    asm volatile("global_store_dwordx2 %0, %1, off sc0 sc1"                            \
                 :: "v"((uint32_t*)(hn + hoff)), "v"(dv) : "memory");                  \
    if (layer) {                                                                       \
      float* outp = out + (size_t)(T) * ACTMAT;                                        \
      *(float4*)(outp + hoff) = make_float4(h0v, h1v, h2v, h3v);                       \
    }                                                                                  \
  } while (0)

  if (layer == 0) {
    for (int t = 0; t < TSTEPS; ++t) {
      f32x4 acc0 = {}, acc1 = {}, acc2 = {}, acc3 = {};
      u32x4 ra0, ra1, ra2, ra3, ra4, ra5, ra6, ra7,
            ra8, ra9, ra10, ra11, ra12, ra13, ra14, ra15;
      const unsigned short* hp = h0 + (size_t)t * ACTMAT + arow + (g4 << 3);
      ISSUE16(hp, ra);                               // speculative: hide RT under x-half
      KHALF_X(xh + (size_t)t * ACTMAT);              // independent work (64 MFMAs)
      VALIDATE(hp, ra);                              // sentinel check, re-issue if stale
      CONSUME_ALL(ra, 64);
      EPILOGUE(t);
    }
  } else {
    for (int t = 0; t < TSTEPS; ++t) {
      f32x4 acc0 = {}, acc1 = {}, acc2 = {}, acc3 = {};
      u32x4 ra0, ra1, ra2, ra3, ra4, ra5, ra6, ra7,
            ra8, ra9, ra10, ra11, ra12, ra13, ra14, ra15;
      u32x4 rb0, rb1, rb2, rb3, rb4, rb5, rb6, rb7,
            rb8, rb9, rb10, rb11, rb12, rb13, rb14, rb15;
      const unsigned short* hpA = h1 + (size_t)t * ACTMAT + arow + (g4 << 3);
      const unsigned short* hpB = h0 + (size_t)(t + 1) * ACTMAT + arow + (g4 << 3);
      ISSUE16(hpA, ra);                              // own h1[t]: almost always landed
      ISSUE16(hpB, rb);                              // layer0's h0[t+1]: the late one
      VALIDATE(hpA, ra);
      CONSUME_ALL(ra, 64);                           // 64 MFMAs hide hpB's round trip
      VALIDATE(hpB, rb);
      CONSUME_ALL(rb, 0);
      EPILOGUE(t);
    }
  }
#undef CONSUME
#undef CONSUME_ALL
#undef LD1
#undef ISSUE16
#undef BAD1
#undef VALIDATE
#undef KHALF_X
#undef EPILOGUE
}

// ---------------- launch ----------------

extern "C" void kernel_launch(void* const* d_in, const int* in_sizes, int n_in,
                              void* d_out, int out_size, void* d_ws, size_t ws_size,
                              hipStream_t stream) {
  (void)in_sizes; (void)n_in; (void)out_size; (void)ws_size;
  const float* x   = (const float*)d_in[0];
  const float* Wi0 = (const float*)d_in[1];
  const float* bi0 = (const float*)d_in[2];
  const float* Wh0 = (const float*)d_in[3];
  const float* Wi1 = (const float*)d_in[4];
  const float* bi1 = (const float*)d_in[5];
  const float* Wh1 = (const float*)d_in[6];
  float* out = (float*)d_out;

  char* ws = (char*)d_ws;
  size_t off = 0;
  auto take = [&](size_t bytes) -> void* {
    void* p = ws + off;
    off += (bytes + 255) & ~(size_t)255;
    return p;
  };
  unsigned short* xh  = (unsigned short*)take((size_t)TSTEPS * ACTMAT * 2);        // 33.5 MB
  unsigned short* h0  = (unsigned short*)take((size_t)(TSTEPS + 1) * ACTMAT * 2);  // 33.6 MB
  unsigned short* h1  = (unsigned short*)take((size_t)(TSTEPS + 1) * ACTMAT * 2);  // 33.6 MB
  unsigned short* Wf0 = (unsigned short*)take((size_t)GATE * 1024 * 2);            // 4 MB
  unsigned short* Wf1 = (unsigned short*)take((size_t)GATE * 1024 * 2);            // 4 MB

  // (TSTEPS+1)*ACTMAT ushorts = 33,619,968 B per buffer -> 2,101,248 16B units
  init_h<<<dim3(8208), dim3(256), 0, stream>>>(h0, h1);
  convert_x<<<dim3(16384), dim3(256), 0, stream>>>(x, xh);
  split_w<<<dim3(8192), dim3(256), 0, stream>>>(Wi0, Wh0, Wf0);
  split_w<<<dim3(8192), dim3(256), 0, stream>>>(Wi1, Wh1, Wf1);
  sublstm_persistent<<<dim3(NWORK), dim3(128), 0, stream>>>(
      xh, h0, h1, Wf0, Wf1, bi0, bi1, out);
}